// Round 6
// baseline (356.630 us; speedup 1.0000x reference)
//
#include <hip/hip_runtime.h>
#include <hip/hip_bf16.h>

// InnocentAttention: B=4 H=16 S=2048 D=64, fp32 in/out, per-batch event_length mask.
// R6: barrier-free, LDS-free flash. Prepass: K->bf16 [key][d], V->bf16 [d][key]
// (+ mean(V) fused). Main kernel: 64-thread (1-wave) blocks, 32 q per item,
// dynamic ticket queue; K/V fragments loaded global->VGPR directly; P stays in
// registers via a permuted PV k-slot mapping (MFMA k-order is free), so the
// C->B layout transform costs zero cross-lane ops. No __syncthreads anywhere.

#define SQ 2048
#define DH 64
#define NBH 64
#define TK 64

typedef __attribute__((ext_vector_type(4))) float f32x4;
typedef __attribute__((ext_vector_type(8))) short bf16x8;
typedef __attribute__((ext_vector_type(4))) unsigned int u32x4;
typedef __attribute__((ext_vector_type(2))) unsigned int u32x2;

__device__ __forceinline__ unsigned int pk2(float lo, float hi) {
    __hip_bfloat162 h = __float22bfloat162_rn(float2{lo, hi});
    union { __hip_bfloat162 h; unsigned int u; } c; c.h = h;
    return c.u;
}

// ---- prepass 1: K fp32 -> bf16, same [key][d] layout ----
__global__ __launch_bounds__(256)
void convert_k(const float* __restrict__ K, unsigned int* __restrict__ Kb) {
    const size_t i = ((size_t)blockIdx.x * 256 + threadIdx.x) * 16;
    const float* p = K + i;
    f32x4 a = *(const f32x4*)p;
    f32x4 b = *(const f32x4*)(p + 4);
    f32x4 c = *(const f32x4*)(p + 8);
    f32x4 d = *(const f32x4*)(p + 12);
    u32x4 o0, o1;
    o0[0] = pk2(a[0], a[1]); o0[1] = pk2(a[2], a[3]);
    o0[2] = pk2(b[0], b[1]); o0[3] = pk2(b[2], b[3]);
    o1[0] = pk2(c[0], c[1]); o1[1] = pk2(c[2], c[3]);
    o1[2] = pk2(d[0], d[1]); o1[3] = pk2(d[2], d[3]);
    *(u32x4*)(Kb + i / 2)     = o0;
    *(u32x4*)(Kb + i / 2 + 4) = o1;
}

// ---- prepass 2: V fp32 [key][d] -> bf16 [d][key] per bh, mean(V) fused ----
__global__ __launch_bounds__(256)
void transpose_v(const float* __restrict__ V, short* __restrict__ Vt,
                 float* __restrict__ MV) {
    const int bh = blockIdx.x >> 5;
    const int k0 = (blockIdx.x & 31) * 64;
    const int t  = threadIdx.x;
    const int kb = t & 15;     // 4-key group
    const int dg = t >> 4;     // 4-d group 0..15
    const float* vp = V + ((size_t)bh * SQ + k0 + kb * 4) * DH + dg * 4;
    f32x4 r0 = *(const f32x4*)vp;
    f32x4 r1 = *(const f32x4*)(vp + DH);
    f32x4 r2 = *(const f32x4*)(vp + 2 * DH);
    f32x4 r3 = *(const f32x4*)(vp + 3 * DH);
    short* op = Vt + ((size_t)bh * DH + dg * 4) * SQ + k0 + kb * 4;
    #pragma unroll
    for (int i = 0; i < 4; ++i) {
        u32x2 w; w[0] = pk2(r0[i], r1[i]); w[1] = pk2(r2[i], r3[i]);
        *(u32x2*)(op + (size_t)i * SQ) = w;
    }
    f32x4 s = r0 + r1 + r2 + r3;
    #pragma unroll
    for (int d = 1; d < 16; d <<= 1) {
        s[0] += __shfl_xor(s[0], d);
        s[1] += __shfl_xor(s[1], d);
        s[2] += __shfl_xor(s[2], d);
        s[3] += __shfl_xor(s[3], d);
    }
    if ((t & 15) == 0) {
        const float inv = 1.0f / (float)SQ;
        atomicAdd(&MV[bh * DH + dg * 4 + 0], s[0] * inv);
        atomicAdd(&MV[bh * DH + dg * 4 + 1], s[1] * inv);
        atomicAdd(&MV[bh * DH + dg * 4 + 2], s[2] * inv);
        atomicAdd(&MV[bh * DH + dg * 4 + 3], s[3] * inv);
    }
}

// ---- main: 1 wave per block, 32 queries per item, no LDS, no barriers ----
__global__ __launch_bounds__(64, 3)
void flash6(const float* __restrict__ Q, const short* __restrict__ Kg,
            const short* __restrict__ Vg, const int* __restrict__ EL,
            const float* __restrict__ MV, float* __restrict__ O,
            int* __restrict__ ticket) {
    const int lane = threadIdx.x;
    const int qd = lane >> 4, c = lane & 15;

    // ---- static phase: masked q-chunks of own (bh,qc) get mean(V) ----
    {
        const int bh0 = blockIdx.x & (NBH - 1);
        const int qb0 = (blockIdx.x >> 6) * 32;
        if (qb0 >= EL[bh0 >> 4]) {
            float* Op = O + (size_t)bh0 * SQ * DH;
            f32x4 mv = *(const f32x4*)(MV + bh0 * DH + c * 4);
            #pragma unroll
            for (int i = 0; i < 8; ++i)
                *(f32x4*)(Op + (size_t)(qb0 + qd + i * 4) * DH + c * 4) = mv;
        }
    }

    // ---- dynamic phase over valid items (bh, 32q-chunk) ----
    const int el0 = EL[0], el1 = EL[1], el2 = EL[2], el3 = EL[3];
    const int v0 = (el0 + 31) >> 5, v1 = (el1 + 31) >> 5;
    const int v2 = (el2 + 31) >> 5, v3 = (el3 + 31) >> 5;
    const int n0 = 16 * v0, n1 = n0 + 16 * v1, n2 = n1 + 16 * v2;
    const int nvalid = n2 + 16 * v3;
    const float sc = 0.125f * 1.44269504f;

    for (;;) {
        int it;
        if (ticket) {
            if (lane == 0) it = atomicAdd(ticket, 1);
            it = __shfl(it, 0);
            if (it >= nvalid) break;
        } else {
            it = blockIdx.x;                 // static fallback (ws too small)
            if (it >= nvalid) break;
        }

        int b, u, vb, el;
        if      (it < n0) { b = 0; u = it;      vb = v0; el = el0; }
        else if (it < n1) { b = 1; u = it - n0; vb = v1; el = el1; }
        else if (it < n2) { b = 2; u = it - n1; vb = v2; el = el2; }
        else              { b = 3; u = it - n2; vb = v3; el = el3; }
        const int head  = u / vb;
        const int qc    = u - head * vb;
        const int bh    = b * 16 + head;
        const int qbase = qc * 32;

        const float* Qp = Q + (size_t)bh * SQ * DH;
        const short* Kp = Kg + (size_t)bh * SQ * DH;   // [key][d] bf16
        const short* Vp = Vg + (size_t)bh * DH * SQ;   // [d][key] bf16
        float* Op = O + (size_t)bh * SQ * DH;

        // Q fragments (B-operand of S^T = K*Q^T)
        bf16x8 qf[2][2];
        #pragma unroll
        for (int nt = 0; nt < 2; ++nt) {
            const int row = qbase + nt * 16 + c;
            #pragma unroll
            for (int kc = 0; kc < 2; ++kc) {
                const float* p = Qp + (size_t)row * DH + kc * 32 + qd * 8;
                f32x4 a  = *(const f32x4*)p;
                f32x4 bb = *(const f32x4*)(p + 4);
                u32x4 f;
                f[0] = pk2(a[0] * sc, a[1] * sc);
                f[1] = pk2(a[2] * sc, a[3] * sc);
                f[2] = pk2(bb[0] * sc, bb[1] * sc);
                f[3] = pk2(bb[2] * sc, bb[3] * sc);
                qf[nt][kc] = *(bf16x8*)&f;
            }
        }

        float l_[2] = {0.f, 0.f};
        f32x4 oacc[4][2];
        #pragma unroll
        for (int dt = 0; dt < 4; ++dt)
            #pragma unroll
            for (int nt = 0; nt < 2; ++nt)
                oacc[dt][nt] = (f32x4){0.f, 0.f, 0.f, 0.f};

        const int nkt = (el + TK - 1) / TK;
        for (int kt = 0; kt < nkt; ++kt) {
            const int k0 = kt * TK;

            // K A-frags: lane holds key k0+mt*16+c, d = kc*32+qd*8..+7 (16B)
            bf16x8 kf[4][2];
            #pragma unroll
            for (int mt = 0; mt < 4; ++mt) {
                const short* kp = Kp + (size_t)(k0 + mt * 16 + c) * DH + qd * 8;
                kf[mt][0] = *(const bf16x8*)kp;
                kf[mt][1] = *(const bf16x8*)(kp + 32);
            }
            // V^T A-frags with permuted k-slots: keys kc*32+qd*4 and +16+qd*4
            u32x4 vf[4][2];
            #pragma unroll
            for (int dt = 0; dt < 4; ++dt) {
                const short* vp = Vp + (size_t)(dt * 16 + c) * SQ + k0 + qd * 4;
                #pragma unroll
                for (int kc = 0; kc < 2; ++kc) {
                    u32x2 aa = *(const u32x2*)(vp + kc * 32);
                    u32x2 bb = *(const u32x2*)(vp + kc * 32 + 16);
                    vf[dt][kc][0] = aa[0]; vf[dt][kc][1] = aa[1];
                    vf[dt][kc][2] = bb[0]; vf[dt][kc][3] = bb[1];
                }
            }

            // S^T = K * Q^T
            f32x4 st[4][2];
            #pragma unroll
            for (int mt = 0; mt < 4; ++mt)
                #pragma unroll
                for (int nt = 0; nt < 2; ++nt) {
                    f32x4 acc = (f32x4){0.f, 0.f, 0.f, 0.f};
                    acc = __builtin_amdgcn_mfma_f32_16x16x32_bf16(kf[mt][0], qf[nt][0], acc, 0, 0, 0);
                    acc = __builtin_amdgcn_mfma_f32_16x16x32_bf16(kf[mt][1], qf[nt][1], acc, 0, 0, 0);
                    st[mt][nt] = acc;
                }

            if (k0 + TK > el) {   // straddling tile: mask invalid keys
                #pragma unroll
                for (int mt = 0; mt < 4; ++mt)
                    #pragma unroll
                    for (int r = 0; r < 4; ++r)
                        if (k0 + mt * 16 + qd * 4 + r >= el) {
                            st[mt][0][r] = -1e30f;
                            st[mt][1][r] = -1e30f;
                        }
            }

            // p = exp2(s) (max-free; scores bounded, softmax shift-invariant)
            u32x2 pd[2][4];     // packed P: [nt][mt] = keys qd*4..+3 of tile mt
            #pragma unroll
            for (int nt = 0; nt < 2; ++nt) {
                #pragma unroll
                for (int mt = 0; mt < 4; ++mt) {
                    const float p0 = exp2f(st[mt][nt][0]);
                    const float p1 = exp2f(st[mt][nt][1]);
                    const float p2 = exp2f(st[mt][nt][2]);
                    const float p3 = exp2f(st[mt][nt][3]);
                    l_[nt] += (p0 + p1) + (p2 + p3);
                    pd[nt][mt][0] = pk2(p0, p1);
                    pd[nt][mt][1] = pk2(p2, p3);
                }
            }

            // O^T += V^T * P^T — B-frag = local concat(pd[2kc], pd[2kc+1])
            #pragma unroll
            for (int kc = 0; kc < 2; ++kc) {
                #pragma unroll
                for (int nt = 0; nt < 2; ++nt) {
                    u32x4 bfr;
                    bfr[0] = pd[nt][2 * kc][0];     bfr[1] = pd[nt][2 * kc][1];
                    bfr[2] = pd[nt][2 * kc + 1][0]; bfr[3] = pd[nt][2 * kc + 1][1];
                    bf16x8 bb = *(bf16x8*)&bfr;
                    #pragma unroll
                    for (int dt = 0; dt < 4; ++dt)
                        oacc[dt][nt] = __builtin_amdgcn_mfma_f32_16x16x32_bf16(
                            *(bf16x8*)&vf[dt][kc], bb, oacc[dt][nt], 0, 0, 0);
                }
            }
        }

        #pragma unroll
        for (int nt = 0; nt < 2; ++nt) {
            l_[nt] += __shfl_xor(l_[nt], 16);
            l_[nt] += __shfl_xor(l_[nt], 32);
        }

        #pragma unroll
        for (int nt = 0; nt < 2; ++nt) {
            const int row = qbase + nt * 16 + c;
            if (row < el) {
                const float inv = 1.0f / l_[nt];
                #pragma unroll
                for (int dt = 0; dt < 4; ++dt) {
                    f32x4 o = oacc[dt][nt];
                    o[0] *= inv; o[1] *= inv; o[2] *= inv; o[3] *= inv;
                    *(f32x4*)(Op + (size_t)row * DH + dt * 16 + qd * 4) = o;
                }
            } else {
                #pragma unroll
                for (int dt = 0; dt < 4; ++dt) {
                    f32x4 mv = *(const f32x4*)(MV + bh * DH + dt * 16 + qd * 4);
                    *(f32x4*)(Op + (size_t)row * DH + dt * 16 + qd * 4) = mv;
                }
            }
        }

        if (!ticket) break;    // static fallback: one item per block
    }
}

extern "C" void kernel_launch(void* const* d_in, const int* in_sizes, int n_in,
                              void* d_out, int out_size, void* d_ws, size_t ws_size,
                              hipStream_t stream) {
    const float* q  = (const float*)d_in[0];
    const float* k  = (const float*)d_in[1];
    const float* v  = (const float*)d_in[2];
    const int*   el = (const int*)d_in[3];
    float* out = (float*)d_out;

    const size_t nelem = (size_t)NBH * SQ * DH;                  // 8.4M
    const size_t need  = 16384 + 2 * nelem * sizeof(short);      // mv + Kb + Vt

    float* mv = (float*)d_ws;
    short* kb = (short*)((char*)d_ws + 16384);
    short* vt = kb + nelem;

    int* tk = nullptr;
    if (ws_size >= need + 8) {        // ticket in workspace tail
        tk = (int*)((char*)d_ws + ((ws_size - 4) & ~(size_t)3));
        hipMemsetAsync(tk, 0, 4, stream);
    }
    hipMemsetAsync(mv, 0, NBH * DH * sizeof(float), stream);
    convert_k<<<dim3((unsigned)(nelem / (256 * 16))), dim3(256), 0, stream>>>(k, (unsigned int*)kb);
    transpose_v<<<dim3(NBH * 32), dim3(256), 0, stream>>>(v, vt, mv);
    flash6<<<dim3(NBH * (SQ / 32)), dim3(64), 0, stream>>>(q, kb, vt, el, mv, out, tk);
}